// Round 4
// baseline (868.314 us; speedup 1.0000x reference)
//
#include <hip/hip_runtime.h>
#include <hip/hip_fp16.h>
#include <math.h>

#define D_IN 32
#define NH 4
#define DH 8

#define BUCKET_BITS 7          // 128 nodes per bucket
#define BUCKET_N    128
#define CHUNK 8192             // edges per partition block
#define QSTRIDE 40             // LDS q row stride in halfs (16B-aligned, bank-spread)

typedef __attribute__((ext_vector_type(8))) _Float16 half8;
typedef __attribute__((ext_vector_type(2))) _Float16 half2v;

__device__ __forceinline__ float fdot8(const _Float16* qa, half8 kb) {
    half2v q0 = {qa[0], qa[1]}, q1 = {qa[2], qa[3]}, q2 = {qa[4], qa[5]}, q3 = {qa[6], qa[7]};
    half2v k0 = {kb[0], kb[1]}, k1 = {kb[2], kb[3]}, k2 = {kb[4], kb[5]}, k3 = {kb[6], kb[7]};
    float acc = 0.f;
    acc = __builtin_amdgcn_fdot2(q0, k0, acc, false);
    acc = __builtin_amdgcn_fdot2(q1, k1, acc, false);
    acc = __builtin_amdgcn_fdot2(q2, k2, acc, false);
    acc = __builtin_amdgcn_fdot2(q3, k3, acc, false);
    return acc;
}

// ---------------------------------------------------------------- K1: QKV
// qh: fp16, pre-scaled by 1/sqrt(8).  kv: fp16 interleaved row [k(32) | v(32)]
__global__ void qkv_kernel(const float* __restrict__ x,
                           const float* __restrict__ Wq,
                           const float* __restrict__ Wk,
                           const float* __restrict__ Wv,
                           _Float16* __restrict__ qh,
                           _Float16* __restrict__ kv,
                           int N) {
    __shared__ float sWq[1024], sWk[1024], sWv[1024];
    for (int i = threadIdx.x; i < 1024; i += blockDim.x) {
        sWq[i] = Wq[i];
        sWk[i] = Wk[i];
        sWv[i] = Wv[i];
    }
    __syncthreads();
    int n = blockIdx.x * blockDim.x + threadIdx.x;
    if (n >= N) return;

    float xr[32];
    const float4* x4 = (const float4*)(x + (size_t)n * 32);
    #pragma unroll
    for (int i = 0; i < 8; i++) {
        float4 f = x4[i];
        xr[4*i+0] = f.x; xr[4*i+1] = f.y; xr[4*i+2] = f.z; xr[4*i+3] = f.w;
    }

    const float scale = 0.35355339059327373f; // 1/sqrt(D_HEAD)
    float acc[32];

    // q -> fp16 (scaled)
    #pragma unroll
    for (int j = 0; j < 32; j++) acc[j] = 0.f;
    for (int i = 0; i < 32; i++) {
        float xi = xr[i];
        #pragma unroll
        for (int j = 0; j < 32; j++) acc[j] += xi * sWq[i*32 + j];
    }
    {
        _Float16* o = qh + (size_t)n * 32;
        #pragma unroll
        for (int i = 0; i < 4; i++) {
            half8 hv;
            #pragma unroll
            for (int j = 0; j < 8; j++) hv[j] = (_Float16)(acc[i*8 + j] * scale);
            *(half8*)(o + i*8) = hv;
        }
    }

    // k -> kv[0..31]
    #pragma unroll
    for (int j = 0; j < 32; j++) acc[j] = 0.f;
    for (int i = 0; i < 32; i++) {
        float xi = xr[i];
        #pragma unroll
        for (int j = 0; j < 32; j++) acc[j] += xi * sWk[i*32 + j];
    }
    {
        _Float16* o = kv + ((size_t)n << 6);
        #pragma unroll
        for (int i = 0; i < 4; i++) {
            half8 hv;
            #pragma unroll
            for (int j = 0; j < 8; j++) hv[j] = (_Float16)acc[i*8 + j];
            *(half8*)(o + i*8) = hv;
        }
    }

    // v -> kv[32..63]
    #pragma unroll
    for (int j = 0; j < 32; j++) acc[j] = 0.f;
    for (int i = 0; i < 32; i++) {
        float xi = xr[i];
        #pragma unroll
        for (int j = 0; j < 32; j++) acc[j] += xi * sWv[i*32 + j];
    }
    {
        _Float16* o = kv + ((size_t)n << 6) + 32;
        #pragma unroll
        for (int i = 0; i < 4; i++) {
            half8 hv;
            #pragma unroll
            for (int j = 0; j < 8; j++) hv[j] = (_Float16)acc[i*8 + j];
            *(half8*)(o + i*8) = hv;
        }
    }
}

// ------------------------------------- K2: coarse per-(bucket,block) counts
__global__ void coarse_hist_kernel(const int* __restrict__ dst,
                                   int* __restrict__ counts,
                                   int E, int nbuckets, int nblocks) {
    __shared__ int h[1024];
    for (int i = threadIdx.x; i < 1024; i += 256) h[i] = 0;
    __syncthreads();
    int base = blockIdx.x * CHUNK;
    int end = min(base + CHUNK, E);
    for (int e = base + threadIdx.x; e < end; e += 256)
        atomicAdd(&h[dst[e] >> BUCKET_BITS], 1);
    __syncthreads();
    for (int i = threadIdx.x; i < nbuckets; i += 256)
        counts[(size_t)i * nblocks + blockIdx.x] = h[i];
}

// ------------------------------------------------ K3a: per-chunk (1024) scan
__global__ void scan1_kernel(const int4* __restrict__ in4,
                             int4* __restrict__ out4,
                             int* __restrict__ bsum) {
    __shared__ int sh[256];
    int t = threadIdx.x;
    int idx = blockIdx.x * 256 + t;
    int4 v = in4[idx];
    int tsum = v.x + v.y + v.z + v.w;
    sh[t] = tsum;
    __syncthreads();
    int incl = tsum;
    for (int o = 1; o < 256; o <<= 1) {
        int u = (t >= o) ? sh[t - o] : 0;
        __syncthreads();
        incl += u;
        sh[t] = incl;
        __syncthreads();
    }
    int excl = incl - tsum;
    out4[idx] = make_int4(excl, excl + v.x, excl + v.x + v.y, excl + v.x + v.y + v.z);
    if (t == 255) bsum[blockIdx.x] = incl;
}

// ------------------------------------------- K3b: scan of block sums (<=512)
__global__ void scan2_kernel(int* __restrict__ bsum, int nb) {
    __shared__ int sh[512];
    int t = threadIdx.x;
    int v = (t < nb) ? bsum[t] : 0;
    sh[t] = v;
    __syncthreads();
    int incl = v;
    for (int o = 1; o < 512; o <<= 1) {
        int u = (t >= o) ? sh[t - o] : 0;
        __syncthreads();
        incl += u;
        sh[t] = incl;
        __syncthreads();
    }
    if (t < nb) bsum[t] = incl - v;  // exclusive
}

// --------------------------------------------------- K3c: add block offsets
__global__ void scan3_kernel(int4* __restrict__ out4, const int* __restrict__ bsum) {
    int add = bsum[blockIdx.x];
    int idx = blockIdx.x * 256 + threadIdx.x;
    int4 v = out4[idx];
    out4[idx] = make_int4(v.x + add, v.y + add, v.z + add, v.w + add);
}

// ----------------------------------- K4: partition edges into coarse buckets
// packed = src | (local_dst << 17)
__global__ void partition_kernel(const int* __restrict__ src,
                                 const int* __restrict__ dst,
                                 const int* __restrict__ base,
                                 unsigned* __restrict__ packed,
                                 int E, int nbuckets, int nblocks) {
    __shared__ int cur[1024];
    for (int i = threadIdx.x; i < 1024; i += 256) cur[i] = 0;
    __syncthreads();
    int b0 = blockIdx.x * CHUNK;
    int end = min(b0 + CHUNK, E);
    for (int e = b0 + threadIdx.x; e < end; e += 256) {
        int d = dst[e];
        int bkt = d >> BUCKET_BITS;
        int r = atomicAdd(&cur[bkt], 1);
        int pos = base[(size_t)bkt * nblocks + blockIdx.x] + r;
        packed[pos] = (unsigned)src[e] | ((unsigned)(d & (BUCKET_N - 1)) << 17);
    }
}

// ------- K5: per-bucket LDS-atomic softmax accumulation + @Wo + residual
// 256 threads per bucket of 128 nodes.
__global__ __launch_bounds__(256) void bucket_kernel(const _Float16* __restrict__ qh,
                                                     const _Float16* __restrict__ kv,
                                                     const unsigned* __restrict__ packed,
                                                     const int* __restrict__ base,
                                                     const float* __restrict__ x,
                                                     const float* __restrict__ Wo,
                                                     float* __restrict__ out,
                                                     int E, int N, int nbuckets, int nblocks) {
    __shared__ float acc[BUCKET_N * 36];       // [node][h*9: denom, msg0..7]
    __shared__ _Float16 sq[BUCKET_N * QSTRIDE];
    __shared__ float sWo[1024];

    int b = blockIdx.x;
    int t = threadIdx.x;
    int node0 = b << BUCKET_BITS;

    for (int i = t; i < BUCKET_N * 36; i += 256) acc[i] = 0.f;
    for (int i = t; i < 1024; i += 256) sWo[i] = Wo[i];
    // stage bucket q rows (fp16, 64B each)
    if (t < BUCKET_N) {
        int n = node0 + t;
        if (n < N) {
            const half8* src8 = (const half8*)(qh + ((size_t)n << 5));
            half8* dst8 = (half8*)(sq + t * QSTRIDE);
            #pragma unroll
            for (int i = 0; i < 4; i++) dst8[i] = src8[i];
        }
    }
    __syncthreads();

    int bstart = base[(size_t)b * nblocks];
    int bend = (b + 1 < nbuckets) ? base[(size_t)(b + 1) * nblocks] : E;
    int units = (bend - bstart) << 2;

    for (int u = t; u < units; u += 256) {
        int e = bstart + (u >> 2);
        int h = u & 3;
        unsigned p = packed[e];
        int ld = p >> 17;
        int s  = p & 0x1FFFF;

        const _Float16* qrow = sq + ld * QSTRIDE + (h << 3);
        half8 ka = *(const half8*)(kv + ((size_t)s << 6) + (h << 3));
        half8 va = *(const half8*)(kv + ((size_t)s << 6) + 32 + (h << 3));

        float sc = fdot8(qrow, ka);
        float w = __expf(sc);          // no max subtraction: |sc| <= ~8

        float* a = acc + ld * 36 + h * 9;
        atomicAdd(a + 0, w);
        #pragma unroll
        for (int j = 0; j < 8; j++)
            atomicAdd(a + 1 + j, w * (float)va[j]);
    }

    __syncthreads();

    // finalize: one thread per node (threads 0..127)
    if (t < BUCKET_N) {
        int n = node0 + t;
        if (n < N) {
            const float* a = acc + t * 36;
            float attn[32];
            #pragma unroll
            for (int h = 0; h < 4; h++) {
                float inv = 1.0f / fmaxf(a[h*9], 1e-16f);
                #pragma unroll
                for (int j = 0; j < 8; j++)
                    attn[h*8 + j] = a[h*9 + 1 + j] * inv;
            }
            float o[32];
            const float4* x4 = (const float4*)(x + (size_t)n * 32);
            #pragma unroll
            for (int i = 0; i < 8; i++) {
                float4 f = x4[i];
                o[4*i+0] = f.x; o[4*i+1] = f.y; o[4*i+2] = f.z; o[4*i+3] = f.w;
            }
            for (int i = 0; i < 32; i++) {
                float ai = attn[i];
                #pragma unroll
                for (int c = 0; c < 32; c++) o[c] += ai * sWo[i*32 + c];  // broadcast row
            }
            float4* o4 = (float4*)(out + (size_t)n * 32);
            #pragma unroll
            for (int i = 0; i < 8; i++)
                o4[i] = make_float4(o[4*i], o[4*i+1], o[4*i+2], o[4*i+3]);
        }
    }
}

extern "C" void kernel_launch(void* const* d_in, const int* in_sizes, int n_in,
                              void* d_out, int out_size, void* d_ws, size_t ws_size,
                              hipStream_t stream) {
    const float* x  = (const float*)d_in[0];
    const float* Wq = (const float*)d_in[1];
    const float* Wk = (const float*)d_in[2];
    const float* Wv = (const float*)d_in[3];
    const float* Wo = (const float*)d_in[4];
    const int*   ei = (const int*)d_in[5];   // int32

    const int N = in_sizes[0] / D_IN;
    const int E = in_sizes[5] / 2;
    const int* src = ei;        // edge_index[0]
    const int* dst = ei + E;    // edge_index[1]

    const int nbuckets = (N + BUCKET_N - 1) >> BUCKET_BITS;  // 782
    const int nblocks  = (E + CHUNK - 1) / CHUNK;            // 391
    const int L    = nbuckets * nblocks;
    const int NB1  = (L + 1023) / 1024;                      // scan chunks (299)
    const int LPAD = NB1 * 1024;

    // workspace layout
    _Float16* qh      = (_Float16*)d_ws;                     // N*32
    _Float16* kv      = qh + (size_t)N * 32;                 // N*64
    int*      scanarr = (int*)(kv + (size_t)N * 64);         // LPAD
    int*      bsum    = scanarr + LPAD;                      // 512
    unsigned* packed  = (unsigned*)(bsum + 512);             // E

    hipMemsetAsync(scanarr, 0, (size_t)LPAD * sizeof(int), stream);

    qkv_kernel<<<(N + 255) / 256, 256, 0, stream>>>(x, Wq, Wk, Wv, qh, kv, N);

    coarse_hist_kernel<<<nblocks, 256, 0, stream>>>(dst, scanarr, E, nbuckets, nblocks);

    scan1_kernel<<<NB1, 256, 0, stream>>>((const int4*)scanarr, (int4*)scanarr, bsum);
    scan2_kernel<<<1, 512, 0, stream>>>(bsum, NB1);
    scan3_kernel<<<NB1, 256, 0, stream>>>((int4*)scanarr, bsum);

    partition_kernel<<<nblocks, 256, 0, stream>>>(src, dst, scanarr, packed,
                                                  E, nbuckets, nblocks);

    bucket_kernel<<<nbuckets, 256, 0, stream>>>(qh, kv, packed, scanarr, x, Wo,
                                                (float*)d_out, E, N, nbuckets, nblocks);
}

// Round 5
// 200.915 us; speedup vs baseline: 4.3218x; 4.3218x over previous
//
#include <hip/hip_runtime.h>
#include <hip/hip_fp16.h>
#include <math.h>

#define D_IN 32
#define NH 4
#define DH 8

#define BUCKET_BITS 8          // 256 nodes per bucket
#define CHUNK 8192             // edges per partition block

typedef __attribute__((ext_vector_type(8))) _Float16 half8;
typedef __attribute__((ext_vector_type(2))) _Float16 half2v;

__device__ __forceinline__ float fdot8v(half8 a, half8 b) {
    half2v a0 = {a[0], a[1]}, a1 = {a[2], a[3]}, a2 = {a[4], a[5]}, a3 = {a[6], a[7]};
    half2v b0 = {b[0], b[1]}, b1 = {b[2], b[3]}, b2 = {b[4], b[5]}, b3 = {b[6], b[7]};
    float acc = 0.f;
    acc = __builtin_amdgcn_fdot2(a0, b0, acc, false);
    acc = __builtin_amdgcn_fdot2(a1, b1, acc, false);
    acc = __builtin_amdgcn_fdot2(a2, b2, acc, false);
    acc = __builtin_amdgcn_fdot2(a3, b3, acc, false);
    return acc;
}

// ---------------------------------------------------------------- K1: QKV
// qh: fp16 pre-scaled by 1/sqrt(8).  kv: fp16 interleaved row [k(32) | v(32)]
__global__ void qkv_kernel(const float* __restrict__ x,
                           const float* __restrict__ Wq,
                           const float* __restrict__ Wk,
                           const float* __restrict__ Wv,
                           _Float16* __restrict__ qh,
                           _Float16* __restrict__ kv,
                           int N) {
    __shared__ float sWq[1024], sWk[1024], sWv[1024];
    for (int i = threadIdx.x; i < 1024; i += blockDim.x) {
        sWq[i] = Wq[i];
        sWk[i] = Wk[i];
        sWv[i] = Wv[i];
    }
    __syncthreads();
    int n = blockIdx.x * blockDim.x + threadIdx.x;
    if (n >= N) return;

    float xr[32];
    const float4* x4 = (const float4*)(x + (size_t)n * 32);
    #pragma unroll
    for (int i = 0; i < 8; i++) {
        float4 f = x4[i];
        xr[4*i+0] = f.x; xr[4*i+1] = f.y; xr[4*i+2] = f.z; xr[4*i+3] = f.w;
    }

    const float scale = 0.35355339059327373f; // 1/sqrt(D_HEAD)
    float acc[32];

    // q -> fp16 (scaled)
    #pragma unroll
    for (int j = 0; j < 32; j++) acc[j] = 0.f;
    for (int i = 0; i < 32; i++) {
        float xi = xr[i];
        #pragma unroll
        for (int j = 0; j < 32; j++) acc[j] += xi * sWq[i*32 + j];
    }
    {
        _Float16* o = qh + ((size_t)n << 5);
        #pragma unroll
        for (int i = 0; i < 4; i++) {
            half8 hv;
            #pragma unroll
            for (int j = 0; j < 8; j++) hv[j] = (_Float16)(acc[i*8 + j] * scale);
            *(half8*)(o + i*8) = hv;
        }
    }

    // k -> kv[0..31]
    #pragma unroll
    for (int j = 0; j < 32; j++) acc[j] = 0.f;
    for (int i = 0; i < 32; i++) {
        float xi = xr[i];
        #pragma unroll
        for (int j = 0; j < 32; j++) acc[j] += xi * sWk[i*32 + j];
    }
    {
        _Float16* o = kv + ((size_t)n << 6);
        #pragma unroll
        for (int i = 0; i < 4; i++) {
            half8 hv;
            #pragma unroll
            for (int j = 0; j < 8; j++) hv[j] = (_Float16)acc[i*8 + j];
            *(half8*)(o + i*8) = hv;
        }
    }

    // v -> kv[32..63]
    #pragma unroll
    for (int j = 0; j < 32; j++) acc[j] = 0.f;
    for (int i = 0; i < 32; i++) {
        float xi = xr[i];
        #pragma unroll
        for (int j = 0; j < 32; j++) acc[j] += xi * sWv[i*32 + j];
    }
    {
        _Float16* o = kv + ((size_t)n << 6) + 32;
        #pragma unroll
        for (int i = 0; i < 4; i++) {
            half8 hv;
            #pragma unroll
            for (int j = 0; j < 8; j++) hv[j] = (_Float16)acc[i*8 + j];
            *(half8*)(o + i*8) = hv;
        }
    }
}

// ------------------------------------- K2: coarse per-(bucket,block) counts
__global__ void coarse_hist_kernel(const int* __restrict__ dst,
                                   int* __restrict__ counts,
                                   int E, int nbuckets, int nblocks) {
    __shared__ int h[512];
    for (int i = threadIdx.x; i < 512; i += 256) h[i] = 0;
    __syncthreads();
    int base = blockIdx.x * CHUNK;
    int end = min(base + CHUNK, E);
    for (int e = base + threadIdx.x; e < end; e += 256)
        atomicAdd(&h[dst[e] >> BUCKET_BITS], 1);
    __syncthreads();
    for (int i = threadIdx.x; i < nbuckets; i += 256)
        counts[(size_t)i * nblocks + blockIdx.x] = h[i];
}

// ------------------------------------------------ K3a: per-chunk (1024) scan
__global__ void scan1_kernel(const int4* __restrict__ in4,
                             int4* __restrict__ out4,
                             int* __restrict__ bsum) {
    __shared__ int sh[256];
    int t = threadIdx.x;
    int idx = blockIdx.x * 256 + t;
    int4 v = in4[idx];
    int tsum = v.x + v.y + v.z + v.w;
    sh[t] = tsum;
    __syncthreads();
    int incl = tsum;
    for (int o = 1; o < 256; o <<= 1) {
        int u = (t >= o) ? sh[t - o] : 0;
        __syncthreads();
        incl += u;
        sh[t] = incl;
        __syncthreads();
    }
    int excl = incl - tsum;
    out4[idx] = make_int4(excl, excl + v.x, excl + v.x + v.y, excl + v.x + v.y + v.z);
    if (t == 255) bsum[blockIdx.x] = incl;
}

// ------------------------------------------- K3b: scan of block sums (<=512)
__global__ void scan2_kernel(int* __restrict__ bsum, int nb) {
    __shared__ int sh[512];
    int t = threadIdx.x;
    int v = (t < nb) ? bsum[t] : 0;
    sh[t] = v;
    __syncthreads();
    int incl = v;
    for (int o = 1; o < 512; o <<= 1) {
        int u = (t >= o) ? sh[t - o] : 0;
        __syncthreads();
        incl += u;
        sh[t] = incl;
        __syncthreads();
    }
    if (t < nb) bsum[t] = incl - v;  // exclusive
}

// --------------------------------------------------- K3c: add block offsets
__global__ void scan3_kernel(int4* __restrict__ out4, const int* __restrict__ bsum) {
    int add = bsum[blockIdx.x];
    int idx = blockIdx.x * 256 + threadIdx.x;
    int4 v = out4[idx];
    out4[idx] = make_int4(v.x + add, v.y + add, v.z + add, v.w + add);
}

// ----------------------------------- K4: partition edges into coarse buckets
__global__ void partition_kernel(const int* __restrict__ src,
                                 const int* __restrict__ dst,
                                 const int* __restrict__ base,
                                 unsigned* __restrict__ packed,
                                 int E, int nbuckets, int nblocks) {
    __shared__ int cur[512];
    for (int i = threadIdx.x; i < 512; i += 256) cur[i] = 0;
    __syncthreads();
    int b0 = blockIdx.x * CHUNK;
    int end = min(b0 + CHUNK, E);
    for (int e = b0 + threadIdx.x; e < end; e += 256) {
        int d = dst[e];
        int bkt = d >> BUCKET_BITS;
        int r = atomicAdd(&cur[bkt], 1);
        int pos = base[(size_t)bkt * nblocks + blockIdx.x] + r;
        packed[pos] = (unsigned)src[e] | ((unsigned)(d & 255) << 20);
    }
}

// --------------- K5: fine sort within bucket + exact node offsets (off[])
__global__ void fine_kernel(const unsigned* __restrict__ packed,
                            const int* __restrict__ base,
                            int* __restrict__ off,
                            int* __restrict__ ssrc,
                            int E, int nbuckets, int nblocks) {
    __shared__ int hist[256];
    __shared__ int sc[256];
    __shared__ int excl[256];
    int b = blockIdx.x;
    int t = threadIdx.x;
    int bstart = base[(size_t)b * nblocks];
    int bend = (b + 1 < nbuckets) ? base[(size_t)(b + 1) * nblocks] : E;

    hist[t] = 0;
    __syncthreads();
    for (int e = bstart + t; e < bend; e += 256)
        atomicAdd(&hist[packed[e] >> 20], 1);
    __syncthreads();

    int vt = hist[t];
    sc[t] = vt;
    __syncthreads();
    int incl = vt;
    for (int o = 1; o < 256; o <<= 1) {
        int u = (t >= o) ? sc[t - o] : 0;
        __syncthreads();
        incl += u;
        sc[t] = incl;
        __syncthreads();
    }
    excl[t] = incl - vt;
    off[b * 256 + t] = bstart + incl - vt;

    hist[t] = 0;  // reuse as cursor
    __syncthreads();

    for (int e = bstart + t; e < bend; e += 256) {
        unsigned p = packed[e];
        int local = p >> 20;
        int r = atomicAdd(&hist[local], 1);
        ssrc[bstart + excl[local] + r] = (int)(p & 0xFFFFFu);
    }
}

// ------------- K6: per-node plain-softmax accumulation + @Wo + residual
// One wave per node. lane = slot*4 + h; 16 edge slots x 4 heads. No atomics,
// no max subtraction (|score| <= ~8 -> exp safe in fp32; verified round 4).
__global__ __launch_bounds__(256) void node_kernel(const _Float16* __restrict__ qh,
                                                   const _Float16* __restrict__ kv,
                                                   const int* __restrict__ off,
                                                   const int* __restrict__ ssrc,
                                                   const float* __restrict__ x,
                                                   const float* __restrict__ Wo,
                                                   float* __restrict__ out,
                                                   int N) {
    __shared__ float sWo[1024];
    __shared__ float sAttn[4][32];
    for (int i = threadIdx.x; i < 1024; i += 256) sWo[i] = Wo[i];
    __syncthreads();

    int wid  = threadIdx.x >> 6;
    int lane = threadIdx.x & 63;
    int n = blockIdx.x * 4 + wid;

    if (n < N) {
        int h    = lane & 3;
        int slot = lane >> 2;
        int e0 = off[n], e1 = off[n + 1];

        half8 qa = *(const half8*)(qh + ((size_t)n << 5) + (h << 3));

        float d = 0.f;
        float msg[8];
        #pragma unroll
        for (int j = 0; j < 8; j++) msg[j] = 0.f;

        for (int base = e0; base < e1; base += 16) {
            int e = base + slot;
            if (e < e1) {
                int s = ssrc[e];
                const _Float16* row = kv + ((size_t)s << 6) + (h << 3);
                half8 ka = *(const half8*)row;
                half8 va = *(const half8*)(row + 32);
                float w = __expf(fdot8v(qa, ka));
                d += w;
                #pragma unroll
                for (int j = 0; j < 8; j++) msg[j] += w * (float)va[j];
            }
        }

        // combine the 16 slots of each head (lanes stride 4): plain sums
        #pragma unroll
        for (int mask = 4; mask < 64; mask <<= 1) {
            d += __shfl_xor(d, mask);
            #pragma unroll
            for (int j = 0; j < 8; j++) msg[j] += __shfl_xor(msg[j], mask);
        }

        float inv = 1.0f / fmaxf(d, 1e-16f);
        if (slot == 0) {
            #pragma unroll
            for (int j = 0; j < 8; j++) sAttn[wid][h * 8 + j] = msg[j] * inv;
        }
    }

    __syncthreads();

    if (n < N && lane < 32) {
        float acc = x[(size_t)n * 32 + lane];
        #pragma unroll
        for (int i = 0; i < 32; i++) acc += sAttn[wid][i] * sWo[i * 32 + lane];
        out[(size_t)n * 32 + lane] = acc;
    }
}

extern "C" void kernel_launch(void* const* d_in, const int* in_sizes, int n_in,
                              void* d_out, int out_size, void* d_ws, size_t ws_size,
                              hipStream_t stream) {
    const float* x  = (const float*)d_in[0];
    const float* Wq = (const float*)d_in[1];
    const float* Wk = (const float*)d_in[2];
    const float* Wv = (const float*)d_in[3];
    const float* Wo = (const float*)d_in[4];
    const int*   ei = (const int*)d_in[5];   // int32

    const int N = in_sizes[0] / D_IN;
    const int E = in_sizes[5] / 2;
    const int* src = ei;        // edge_index[0]
    const int* dst = ei + E;    // edge_index[1]

    const int nbuckets = (N + 255) >> BUCKET_BITS;          // 391
    const int nblocks  = (E + CHUNK - 1) / CHUNK;           // 391
    const int L    = nbuckets * nblocks;
    const int NB1  = (L + 1023) / 1024;                     // scan chunks
    const int LPAD = NB1 * 1024;

    // workspace layout
    _Float16* qh      = (_Float16*)d_ws;                    // N*32 halfs
    _Float16* kv      = qh + (size_t)N * 32;                // N*64 halfs
    int*      scanarr = (int*)(kv + (size_t)N * 64);        // LPAD ints
    int*      bsum    = scanarr + LPAD;                     // 512 ints
    int*      off     = bsum + 512;                         // nbuckets*256+64
    unsigned* packed  = (unsigned*)(off + (size_t)nbuckets * 256 + 64);
    int*      ssrc    = (int*)(packed + (size_t)E);

    hipMemsetAsync(scanarr, 0, (size_t)LPAD * sizeof(int), stream);

    qkv_kernel<<<(N + 255) / 256, 256, 0, stream>>>(x, Wq, Wk, Wv, qh, kv, N);

    coarse_hist_kernel<<<nblocks, 256, 0, stream>>>(dst, scanarr, E, nbuckets, nblocks);

    scan1_kernel<<<NB1, 256, 0, stream>>>((const int4*)scanarr, (int4*)scanarr, bsum);
    scan2_kernel<<<1, 512, 0, stream>>>(bsum, NB1);
    scan3_kernel<<<NB1, 256, 0, stream>>>((int4*)scanarr, bsum);

    partition_kernel<<<nblocks, 256, 0, stream>>>(src, dst, scanarr, packed,
                                                  E, nbuckets, nblocks);

    fine_kernel<<<nbuckets, 256, 0, stream>>>(packed, scanarr, off, ssrc,
                                              E, nbuckets, nblocks);

    node_kernel<<<(N + 3) / 4, 256, 0, stream>>>(qh, kv, off, ssrc, x, Wo,
                                                 (float*)d_out, N);
}